// Round 7
// baseline (125.007 us; speedup 1.0000x reference)
//
#include <hip/hip_runtime.h>
#include <hip/hip_bf16.h>
#include <stdint.h>

#define NH 16
#define HID 1024
#define HD 64
#define NB 4
#define SS 1024
#define MTOT (NB*SS)   // 4096

typedef __attribute__((ext_vector_type(8))) short bf16x8;
typedef __attribute__((ext_vector_type(4))) float f32x4;
typedef __attribute__((ext_vector_type(16))) float f32x16;

#define LOG2E 1.44269504088896f

__device__ __forceinline__ unsigned short f2bf(float f) {
  union { float f; unsigned u; } v; v.f = f;
  unsigned u = v.u;
  return (unsigned short)((u + 0x7FFFu + ((u >> 16) & 1u)) >> 16);
}

__device__ __forceinline__ unsigned cvtpk(float lo, float hi) {
  unsigned r;
  asm("v_cvt_pk_bf16_f32 %0, %1, %2" : "=v"(r) : "v"(lo), "v"(hi));
  return r;
}

__device__ __forceinline__ void pl32swap(unsigned &a, unsigned &b) {
  asm("v_permlane32_swap_b32 %0, %1" : "+v"(a), "+v"(b));
}

__device__ __forceinline__ float exp2fast(float x) {
  float r;
  asm("v_exp_f32 %0, %1" : "=v"(r) : "v"(x));
  return r;
}

__device__ __forceinline__ void async16(void* lds, const void* g) {
  __builtin_amdgcn_global_load_lds(
      (const __attribute__((address_space(1))) unsigned*)g,
      (__attribute__((address_space(3))) unsigned*)lds, 16, 0, 0);
}

// ---------------- fp32 -> bf16 conversion of X and W ----------------
__global__ void cvt_all(const float4* __restrict__ X,
                        const float4* __restrict__ Wq,
                        const float4* __restrict__ Wk,
                        const float4* __restrict__ Wv,
                        ushort4* __restrict__ Xb,
                        ushort4* __restrict__ Wb) {
  int i = blockIdx.x * 256 + threadIdx.x;   // 1835008 total
  const float4* src; ushort4* dst; int idx;
  if (i < (MTOT * HID / 4)) {
    src = X; dst = Xb; idx = i;
  } else {
    int j = i - (MTOT * HID / 4);
    int sel = j >> 18;
    idx = j & 262143;
    src = (sel == 0) ? Wq : (sel == 1) ? Wk : Wv;
    dst = Wb + (size_t)sel * 262144;
  }
  float4 v = src[idx];
  ushort4 o;
  o.x = f2bf(v.x); o.y = f2bf(v.y); o.z = f2bf(v.z); o.w = f2bf(v.w);
  dst[idx] = o;
}

// ---------------- fused QKV projection GEMM ----------------
// BM=128 x BN=256, 4 waves x (64x128 out), BK=32 triple-buffered,
// 1 barrier/step, counted vmcnt(6), XOR-swizzled LDS.
// Q pre-scaled by 0.125*log2(e) so attention softmax runs in exp2 domain.
__global__ __launch_bounds__(256) void qkv_gemm(
    const ushort* __restrict__ Xb,    // [4096][1024] bf16
    const ushort* __restrict__ Wb,    // [3072][1024] bf16 (Wq|Wk|Wv)
    const float* __restrict__ bq,
    const float* __restrict__ bk,
    const float* __restrict__ bv,
    ushort* __restrict__ Q,           // [B*H][S][64]
    ushort* __restrict__ K,           // [B*H][S][64]
    ushort* __restrict__ Vt)          // [B*H][64][S]
{
  __shared__ __attribute__((aligned(16))) ushort Al[3][128 * 32]; // 3x8KB
  __shared__ __attribute__((aligned(16))) ushort Bl[3][256 * 32]; // 3x16KB

  int bid = blockIdx.x;               // 384 blocks
  int swz = (bid & 7) * 48 + (bid >> 3);  // XCD swizzle (384 % 8 == 0)
  const int nbn = 3072 / 256;         // 12
  int bm = swz / nbn, bn = swz % nbn;
  int m0 = bm * 128, n0 = bn * 256;

  int tid = threadIdx.x;
  int wave = tid >> 6, lane = tid & 63;
  int g = lane >> 4, c = lane & 15;
  int wr = wave >> 1, wc = wave & 1;  // 2x2 waves, each 64(row) x 128(col)

  // staging: per step each thread issues 2 A-loads + 4 B-loads (16B each).
  // LDS dest linear; bank swizzle via XOR on the GLOBAL 16B-chunk index:
  // position p of row r holds logical chunk p ^ ((r>>1)&3).
  int srow = tid >> 2;                // 0..63
  int schunk = tid & 3;
  int ssw = (srow >> 1) & 3;          // invariant to row+64k
  const ushort* Asrc0 = Xb + (size_t)(m0 + srow) * 1024 + ((schunk ^ ssw) << 3);
  const ushort* Asrc1 = Xb + (size_t)(m0 + 64 + srow) * 1024 + ((schunk ^ ssw) << 3);
  const ushort* Bsrc0 = Wb + (size_t)(n0 + srow) * 1024 + ((schunk ^ ssw) << 3);
  const ushort* Bsrc1 = Wb + (size_t)(n0 + 64 + srow) * 1024 + ((schunk ^ ssw) << 3);
  const ushort* Bsrc2 = Wb + (size_t)(n0 + 128 + srow) * 1024 + ((schunk ^ ssw) << 3);
  const ushort* Bsrc3 = Wb + (size_t)(n0 + 192 + srow) * 1024 + ((schunk ^ ssw) << 3);
  int soff = srow * 64 + schunk * 16;

#define GSTAGE(bi) do {                                   \
    char* la_ = (char*)Al[bi]; char* lb_ = (char*)Bl[bi]; \
    async16(la_ + soff,         Asrc0);                   \
    async16(la_ + 4096 + soff,  Asrc1);                   \
    async16(lb_ + soff,         Bsrc0);                   \
    async16(lb_ + 4096 + soff,  Bsrc1);                   \
    async16(lb_ + 8192 + soff,  Bsrc2);                   \
    async16(lb_ + 12288 + soff, Bsrc3);                   \
    Asrc0 += 32; Asrc1 += 32;                             \
    Bsrc0 += 32; Bsrc1 += 32; Bsrc2 += 32; Bsrc3 += 32;   \
  } while (0)

  f32x4 acc[4][8] = {};
  int rsw = (c >> 1) & 3;             // read-side swizzle
  int ch = ((g ^ rsw) << 4);          // swizzled 16B chunk byte offset

  GSTAGE(0);                          // prologue: 2 steps in flight
  GSTAGE(1);

  int cur = 0, nxt = 2;
  for (int ks = 0; ks < 32; ++ks) {
    if (ks < 31) {
      asm volatile("s_waitcnt vmcnt(6)" ::: "memory");  // cur landed, next in flight
    } else {
      asm volatile("s_waitcnt vmcnt(0)" ::: "memory");
    }
    __builtin_amdgcn_sched_barrier(0);
    __builtin_amdgcn_s_barrier();     // all waves: cur tile complete
    __builtin_amdgcn_sched_barrier(0);
    if (ks < 30) GSTAGE(nxt);         // safe: all waves past reads of buf[nxt]

    const char* la = (const char*)Al[cur];
    const char* lb = (const char*)Bl[cur];
    bf16x8 a[4], b[8];
    #pragma unroll
    for (int m = 0; m < 4; ++m)
      a[m] = *(const bf16x8*)(la + (wr * 64 + m * 16 + c) * 64 + ch);
    #pragma unroll
    for (int n = 0; n < 8; ++n)
      b[n] = *(const bf16x8*)(lb + (wc * 128 + n * 16 + c) * 64 + ch);
    __builtin_amdgcn_s_setprio(1);
    #pragma unroll
    for (int m = 0; m < 4; ++m)
      #pragma unroll
      for (int n = 0; n < 8; ++n)
        acc[m][n] = __builtin_amdgcn_mfma_f32_16x16x32_bf16(a[m], b[n], acc[m][n], 0, 0, 0);
    __builtin_amdgcn_s_setprio(0);

    cur = (cur == 2) ? 0 : cur + 1;
    nxt = (nxt == 2) ? 0 : nxt + 1;
  }
#undef GSTAGE

  int sel = n0 >> 10;                 // uniform per block (256 | 1024)
  const float* bp = (sel == 0) ? bq : (sel == 1) ? bk : bv;
  float scl = (sel == 0) ? 0.125f * LOG2E : 1.0f;

  #pragma unroll
  for (int n = 0; n < 8; ++n) {
    int nn = (n0 & 1023) + wc * 128 + n * 16 + c;
    float bias = bp[nn];
    int h = nn >> 6, d = nn & 63;
    #pragma unroll
    for (int m = 0; m < 4; ++m) {
      int rowg = m0 + wr * 64 + m * 16 + g * 4;
      int bb = rowg >> 10;
      int s = rowg & 1023;
      #pragma unroll
      for (int r = 0; r < 4; ++r) {
        float val = (acc[m][n][r] + bias) * scl;
        unsigned short ob = f2bf(val);
        if (sel == 0)
          Q[(size_t)((bb * 16 + h) * 1024 + s + r) * 64 + d] = ob;
        else if (sel == 1)
          K[(size_t)((bb * 16 + h) * 1024 + s + r) * 64 + d] = ob;
        else
          Vt[(size_t)((bb * 16 + h) * 64 + d) * 1024 + s + r] = ob;
      }
    }
  }
}

// Build two PV A-fragments from 16 P values (C-layout) — 8 cvt_pk + 4
// permlane32_swap, no LDS.
__device__ __forceinline__ void build_pa(const f32x16& p, bf16x8& pa0, bf16x8& pa1) {
  unsigned W0 = cvtpk(p[0],  p[1]);
  unsigned W1 = cvtpk(p[2],  p[3]);
  unsigned W2 = cvtpk(p[4],  p[5]);
  unsigned W3 = cvtpk(p[6],  p[7]);
  unsigned W4 = cvtpk(p[8],  p[9]);
  unsigned W5 = cvtpk(p[10], p[11]);
  unsigned W6 = cvtpk(p[12], p[13]);
  unsigned W7 = cvtpk(p[14], p[15]);
  pl32swap(W0, W2);
  pl32swap(W1, W3);
  pl32swap(W4, W6);
  pl32swap(W5, W7);
  union { unsigned u[4]; bf16x8 v; } a0, a1;
  a0.u[0] = W0; a0.u[1] = W1; a0.u[2] = W2; a0.u[3] = W3;
  a1.u[0] = W4; a1.u[1] = W5; a1.u[2] = W6; a1.u[3] = W7;
  pa0 = a0.v; pa1 = a1.v;
}

// ---------------- flash attention, 32x32 swapped orientation ----------------
// Triple-buffered K/V staging, 1 barrier/iter, mask in LDS (vmcnt stays clean).
__global__ __launch_bounds__(256) void attn(
    const ushort* __restrict__ Q,    // [B*H][S][64], pre-scaled 0.125*log2e
    const ushort* __restrict__ K,    // [B*H][S][64]
    const ushort* __restrict__ Vt,   // [B*H][64][S]
    const float* __restrict__ mask,  // [B][S]
    float* __restrict__ out)         // [B][S][1024]
{
  __shared__ __attribute__((aligned(16))) char kv_lds[3][16384]; // [K 8K][V 8K] x3
  __shared__ float mask_s[SS];                                   // 4 KB (log2-domain)

  int blk = blockIdx.x;           // 512
  int xcd = blk & 7;
  int j = blk >> 3;               // 0..63
  int bh = xcd * 8 + (j >> 3);    // 8 heads per XCD
  int qt = j & 7;
  int b = bh >> 4, h = bh & 15;
  int tid = threadIdx.x, wave = tid >> 6, lane = tid & 63;
  int r31 = lane & 31, hi = lane >> 5;
  int rsw = r31 & 7;
  int hib = hi << 4;
  int q0 = qt * 128 + wave * 32;

  const ushort* Qb = Q + (size_t)bh * SS * 64;
  const ushort* Kb = K + (size_t)bh * SS * 64;
  const ushort* Vb = Vt + (size_t)bh * 64 * SS;

  // mask to LDS, pre-multiplied by log2e (off the vmcnt path in the loop)
  for (int i = tid; i < SS; i += 256) mask_s[i] = mask[b * SS + i] * LOG2E;

  bf16x8 qf[4];
  #pragma unroll
  for (int kp = 0; kp < 4; ++kp)
    qf[kp] = *(const bf16x8*)(Qb + (size_t)(q0 + r31) * 64 + kp * 16 + hi * 8);

  int srow = lane >> 3;
  int schunk = lane & 7;
  const ushort* sptr[4];
  int soff[4];
  #pragma unroll
  for (int j2 = 0; j2 < 4; ++j2) {
    soff[j2] = wave * 4096 + j2 * 1024;
    if (wave < 2) {
      int row = wave * 32 + j2 * 8 + srow;
      sptr[j2] = Kb + (size_t)row * 64 + ((schunk ^ srow) << 3);
    } else {
      int d = (wave - 2) * 32 + j2 * 8 + srow;
      sptr[j2] = Vb + (size_t)d * SS + ((schunk ^ srow) << 3);
    }
  }
  const int sstep = (wave < 2) ? 64 * 64 : 64;

#define STAGE(bufidx) do {                              \
    char* lb_ = kv_lds[bufidx];                         \
    async16(lb_ + soff[0], sptr[0]);                    \
    async16(lb_ + soff[1], sptr[1]);                    \
    async16(lb_ + soff[2], sptr[2]);                    \
    async16(lb_ + soff[3], sptr[3]);                    \
    sptr[0] += sstep; sptr[1] += sstep;                 \
    sptr[2] += sstep; sptr[3] += sstep;                 \
  } while (0)

  __syncthreads();                // mask_s visible to all waves
  STAGE(0);                       // prologue: 2 tiles in flight
  STAGE(1);

  f32x16 o0 = (f32x16)0.0f, o1 = (f32x16)0.0f;
  float mrow = 0.f, lrow = 0.f;

  int cur = 0, nxt = 2;
  for (int it = 0; it < 16; ++it) {
    if (it < 15) {
      asm volatile("s_waitcnt vmcnt(4)" ::: "memory");
    } else {
      asm volatile("s_waitcnt vmcnt(0)" ::: "memory");
    }
    __builtin_amdgcn_sched_barrier(0);
    __builtin_amdgcn_s_barrier();
    __builtin_amdgcn_sched_barrier(0);
    if (it < 14) STAGE(nxt);

    const char* kb0 = kv_lds[cur];
    const char* vb0 = kv_lds[cur] + 8192;

    f32x16 s0 = (f32x16)0.0f, s1 = (f32x16)0.0f;
    __builtin_amdgcn_s_setprio(1);
    #pragma unroll
    for (int kp = 0; kp < 4; ++kp) {
      int ch = (((kp << 1) | hi) ^ rsw) << 4;
      bf16x8 ka = *(const bf16x8*)(kb0 + r31 * 128 + ch);
      bf16x8 kc = *(const bf16x8*)(kb0 + (32 + r31) * 128 + ch);
      s0 = __builtin_amdgcn_mfma_f32_32x32x16_bf16(ka, qf[kp], s0, 0, 0, 0);
      s1 = __builtin_amdgcn_mfma_f32_32x32x16_bf16(kc, qf[kp], s1, 0, 0, 0);
    }
    __builtin_amdgcn_s_setprio(0);

    int kv = it * 64;
    #pragma unroll
    for (int sq = 0; sq < 4; ++sq) {
      f32x4 mk0 = *(const f32x4*)(&mask_s[kv + sq * 8 + hi * 4]);
      f32x4 mk1 = *(const f32x4*)(&mask_s[kv + 32 + sq * 8 + hi * 4]);
      #pragma unroll
      for (int r = 0; r < 4; ++r) {
        s0[sq * 4 + r] += mk0[r];
        s1[sq * 4 + r] += mk1[r];
      }
    }

    float mx = s0[0];
    #pragma unroll
    for (int i = 1; i < 16; ++i) mx = fmaxf(mx, s0[i]);
    #pragma unroll
    for (int i = 0; i < 16; ++i) mx = fmaxf(mx, s1[i]);
    mx = fmaxf(mx, __shfl_xor(mx, 32));

    if (!__all(mx <= mrow + 11.5416f)) {
      float mn = fmaxf(mrow, mx);
      float sc = exp2fast(mrow - mn);
      mrow = mn;
      lrow *= sc;
      #pragma unroll
      for (int i = 0; i < 16; ++i) {
        int qh = (i & 3) + 8 * (i >> 2);
        float scq = __uint_as_float((unsigned)__builtin_amdgcn_ds_bpermute(
            (qh << 2) + hib, (int)__float_as_uint(sc)));
        o0[i] *= scq; o1[i] *= scq;
      }
    }

    f32x16 p0, p1;
    float rs = 0.f;
    #pragma unroll
    for (int i = 0; i < 16; ++i) { float e = exp2fast(s0[i] - mrow); p0[i] = e; rs += e; }
    #pragma unroll
    for (int i = 0; i < 16; ++i) { float e = exp2fast(s1[i] - mrow); p1[i] = e; rs += e; }
    rs += __shfl_xor(rs, 32);
    lrow += rs;

    #pragma unroll
    for (int T = 0; T < 2; ++T) {
      bf16x8 pa0, pa1;
      build_pa(T ? p1 : p0, pa0, pa1);
      __builtin_amdgcn_s_setprio(1);
      #pragma unroll
      for (int kh = 0; kh < 2; ++kh) {
        int kap = 2 * T + kh;
        int ch = (((kap << 1) | hi) ^ rsw) << 4;
        bf16x8 va = *(const bf16x8*)(vb0 + r31 * 128 + ch);
        bf16x8 vc = *(const bf16x8*)(vb0 + (32 + r31) * 128 + ch);
        bf16x8 pf = kh ? pa1 : pa0;
        o0 = __builtin_amdgcn_mfma_f32_32x32x16_bf16(pf, va, o0, 0, 0, 0);
        o1 = __builtin_amdgcn_mfma_f32_32x32x16_bf16(pf, vc, o1, 0, 0, 0);
      }
      __builtin_amdgcn_s_setprio(0);
    }

    cur = (cur == 2) ? 0 : cur + 1;
    nxt = (nxt == 2) ? 0 : nxt + 1;
  }
#undef STAGE

  float inv = 1.0f / lrow;
  #pragma unroll
  for (int i = 0; i < 16; ++i) {
    int qh = (i & 3) + 8 * (i >> 2);
    float li = __uint_as_float((unsigned)__builtin_amdgcn_ds_bpermute(
        (qh << 2) + hib, (int)__float_as_uint(inv)));
    int row = q0 + qh + 4 * hi;
    float* op = out + (size_t)(b * SS + row) * 1024 + h * 64 + r31;
    op[0]  = o0[i] * li;
    op[32] = o1[i] * li;
  }
}

extern "C" void kernel_launch(void* const* d_in, const int* in_sizes, int n_in,
                              void* d_out, int out_size, void* d_ws, size_t ws_size,
                              hipStream_t stream) {
  const float* hs   = (const float*)d_in[0];
  const float* mask = (const float*)d_in[1];
  const float* Wq   = (const float*)d_in[2];
  const float* bq   = (const float*)d_in[3];
  const float* Wk   = (const float*)d_in[4];
  const float* bk   = (const float*)d_in[5];
  const float* Wv   = (const float*)d_in[6];
  const float* bv   = (const float*)d_in[7];
  float* out = (float*)d_out;

  char* ws = (char*)d_ws;
  ushort* Xb = (ushort*)(ws);                    // 8 MB  [4096][1024]
  ushort* Wb = (ushort*)(ws + (8u  << 20));      // 6 MB  [3072][1024]
  ushort* Qp = (ushort*)(ws + (14u << 20));      // 8 MB  [64][1024][64]
  ushort* Kp = (ushort*)(ws + (22u << 20));      // 8 MB  [64][1024][64]
  ushort* Vt = (ushort*)(ws + (30u << 20));      // 8 MB  [64][64][1024]

  cvt_all<<<7168, 256, 0, stream>>>((const float4*)hs, (const float4*)Wq,
                                    (const float4*)Wk, (const float4*)Wv,
                                    (ushort4*)Xb, (ushort4*)Wb);
  qkv_gemm<<<384, 256, 0, stream>>>(Xb, Wb, bq, bk, bv, Qp, Kp, Vt);
  attn<<<512, 256, 0, stream>>>(Qp, Kp, Vt, mask, out);
}

// Round 8
// 98.893 us; speedup vs baseline: 1.2641x; 1.2641x over previous
//
#include <hip/hip_runtime.h>
#include <hip/hip_bf16.h>
#include <stdint.h>

#define NH 16
#define HID 1024
#define HD 64
#define NB 4
#define SS 1024
#define MTOT (NB*SS)   // 4096

typedef __attribute__((ext_vector_type(8))) short bf16x8;
typedef __attribute__((ext_vector_type(4))) float f32x4;
typedef __attribute__((ext_vector_type(16))) float f32x16;

#define LOG2E 1.44269504088896f

__device__ __forceinline__ unsigned short f2bf(float f) {
  union { float f; unsigned u; } v; v.f = f;
  unsigned u = v.u;
  return (unsigned short)((u + 0x7FFFu + ((u >> 16) & 1u)) >> 16);
}

__device__ __forceinline__ unsigned cvtpk(float lo, float hi) {
  unsigned r;
  asm("v_cvt_pk_bf16_f32 %0, %1, %2" : "=v"(r) : "v"(lo), "v"(hi));
  return r;
}

__device__ __forceinline__ void pl32swap(unsigned &a, unsigned &b) {
  asm("v_permlane32_swap_b32 %0, %1" : "+v"(a), "+v"(b));
}

__device__ __forceinline__ float exp2fast(float x) {
  float r;
  asm("v_exp_f32 %0, %1" : "=v"(r) : "v"(x));
  return r;
}

__device__ __forceinline__ void async16(void* lds, const void* g) {
  __builtin_amdgcn_global_load_lds(
      (const __attribute__((address_space(1))) unsigned*)g,
      (__attribute__((address_space(3))) unsigned*)lds, 16, 0, 0);
}

// ---------------- fp32 -> bf16 conversion of X and W ----------------
__global__ void cvt_all(const float4* __restrict__ X,
                        const float4* __restrict__ Wq,
                        const float4* __restrict__ Wk,
                        const float4* __restrict__ Wv,
                        ushort4* __restrict__ Xb,
                        ushort4* __restrict__ Wb) {
  int i = blockIdx.x * 256 + threadIdx.x;   // 1835008 total
  const float4* src; ushort4* dst; int idx;
  if (i < (MTOT * HID / 4)) {
    src = X; dst = Xb; idx = i;
  } else {
    int j = i - (MTOT * HID / 4);
    int sel = j >> 18;
    idx = j & 262143;
    src = (sel == 0) ? Wq : (sel == 1) ? Wk : Wv;
    dst = Wb + (size_t)sel * 262144;
  }
  float4 v = src[idx];
  ushort4 o;
  o.x = f2bf(v.x); o.y = f2bf(v.y); o.z = f2bf(v.z); o.w = f2bf(v.w);
  dst[idx] = o;
}

// ---------------- fused QKV projection GEMM: 256x256 8-phase ----------------
// BM=BN=256, BK=64, 512 thr (2Mx4N waves, 128x64/wave), 128KB LDS,
// 8 phases / 2 K-tiles, counted vmcnt(4) at phases 4&8 only (T2+T3+T4+T5).
// Q pre-scaled by 0.125*log2(e) so attention softmax runs in exp2 domain.
__global__ __launch_bounds__(512, 2) void qkv_gemm(
    const ushort* __restrict__ Xb,    // [4096][1024] bf16
    const ushort* __restrict__ Wb,    // [3072][1024] bf16 (Wq|Wk|Wv)
    const float* __restrict__ bq,
    const float* __restrict__ bk,
    const float* __restrict__ bv,
    ushort* __restrict__ Q,           // [B*H][S][64]
    ushort* __restrict__ K,           // [B*H][S][64]
    ushort* __restrict__ Vt)          // [B*H][64][S]
{
  __shared__ __attribute__((aligned(16))) char lds_[131072]; // A 64K | B 64K
  char* ldsA = lds_;
  char* ldsB = lds_ + 65536;

  int bid = blockIdx.x;                 // 192
  int swz = (bid & 7) * 24 + (bid >> 3);  // XCD swizzle (192 % 8 == 0)
  int bm = swz / 12, bn = swz % 12;
  int m0 = bm * 256, n0 = bn * 256;

  int tid = threadIdx.x;
  int wave = tid >> 6, lane = tid & 63;
  int g = lane >> 4, c = lane & 15;
  int wr = wave >> 2, wc = wave & 3;    // wave owns rows wr*128.., cols wc*64..

  // staging: half-tile = 128 rows x 64 K x 2B = 16KB = 512thr x 2 x 16B.
  // LDS position (row, ck) holds global chunk ck ^ (row&7)  (XOR swizzle).
  int r0 = tid >> 3, ck = tid & 7;
  int gck = ck ^ (r0 & 7);              // same for r0 and r0+64
  const ushort* As0 = Xb + (size_t)(m0 + r0) * 1024 + gck * 8;
  const ushort* As1 = As0 + 128 * 1024;
  const ushort* Bs0 = Wb + (size_t)(n0 + r0) * 1024 + gck * 8;
  const ushort* Bs1 = Bs0 + 128 * 1024;
  int sdst = tid * 16;

#define STG_A(d, h, t) do { \
    const ushort* _s = ((h) ? As1 : As0) + (t) * 64; \
    char* _d = ldsA + ((d) * 2 + (h)) * 16384 + sdst; \
    async16(_d, _s); async16(_d + 8192, _s + 64 * 1024); } while (0)
#define STG_B(d, h, t) do { \
    const ushort* _s = ((h) ? Bs1 : Bs0) + (t) * 64; \
    char* _d = ldsB + ((d) * 2 + (h)) * 16384 + sdst; \
    async16(_d, _s); async16(_d + 8192, _s + 64 * 1024); } while (0)

  // read-side swizzled chunk offsets (row&7 == c&7 since 16 | row-c)
  int ch0 = (g ^ (c & 7)) << 4;         // kk=0: chunk g
  int ch1 = ((4 + g) ^ (c & 7)) << 4;   // kk=1: chunk 4+g

  bf16x8 a[4][2], b[2][2], b2[2][2];
  f32x4 acc[8][4] = {};

#define LDA_(mlo, d) do { \
    const char* _p = ldsA + ((d) * 2 + wr) * 16384; \
    _Pragma("unroll") \
    for (int mm = 0; mm < 4; ++mm) { \
      int _ro = ((mlo) * 64 + mm * 16 + c) * 128; \
      a[mm][0] = *(const bf16x8*)(_p + _ro + ch0); \
      a[mm][1] = *(const bf16x8*)(_p + _ro + ch1); } } while (0)
#define LDB_(dst, nlo, d) do { \
    const char* _p = ldsB + ((d) * 2 + (wc >> 1)) * 16384 + ((wc & 1) * 64) * 128; \
    _Pragma("unroll") \
    for (int nn2 = 0; nn2 < 2; ++nn2) { \
      int _ro = (((nlo) * 2 + nn2) * 16 + c) * 128; \
      dst[nn2][0] = *(const bf16x8*)(_p + _ro + ch0); \
      dst[nn2][1] = *(const bf16x8*)(_p + _ro + ch1); } } while (0)

#define BARRIER() do { __builtin_amdgcn_sched_barrier(0); \
    __builtin_amdgcn_s_barrier(); __builtin_amdgcn_sched_barrier(0); } while (0)

#define MF_(mlo, bf, nlo) do { \
    __builtin_amdgcn_s_setprio(1); \
    _Pragma("unroll") \
    for (int mm = 0; mm < 4; ++mm) \
      _Pragma("unroll") \
      for (int nn2 = 0; nn2 < 2; ++nn2) { \
        acc[(mlo)*4+mm][(nlo)*2+nn2] = __builtin_amdgcn_mfma_f32_16x16x32_bf16( \
            a[mm][0], bf[nn2][0], acc[(mlo)*4+mm][(nlo)*2+nn2], 0, 0, 0); \
        acc[(mlo)*4+mm][(nlo)*2+nn2] = __builtin_amdgcn_mfma_f32_16x16x32_bf16( \
            a[mm][1], bf[nn2][1], acc[(mlo)*4+mm][(nlo)*2+nn2], 0, 0, 0); } \
    __builtin_amdgcn_s_setprio(0); } while (0)

  // prologue: tile0 (buf0) all 4 halves + tile1 (buf1) B halves
  STG_B(0, 0, 0); STG_B(0, 1, 0);
  STG_A(0, 0, 0); STG_A(0, 1, 0);
  STG_B(1, 0, 1); STG_B(1, 1, 1);
  asm volatile("s_waitcnt vmcnt(4)" ::: "memory");   // tile0 halves landed
  BARRIER();

  for (int i2 = 0; i2 < 8; ++i2) {
    int t1 = 2 * i2 + 1, t2 = 2 * i2 + 2, t3 = 2 * i2 + 3;
    // ---- tile 2*i2 (buf0) ----
    // P1: quadrant (m0-3 x n0-1)
    LDA_(0, 0); LDB_(b, 0, 0);
    STG_A(1, 0, t1);
    BARRIER();
    MF_(0, b, 0);
    BARRIER();
    // P2: (m0-3 x n2-3)
    LDB_(b2, 1, 0);
    STG_A(1, 1, t1);
    BARRIER();
    MF_(0, b2, 1);
    BARRIER();
    // P3: (m4-7 x n0-1)   [buf0-B frees after P2, buf0-A after P3]
    LDA_(1, 0);
    STG_B(0, 0, t2);
    BARRIER();
    MF_(1, b, 0);
    BARRIER();
    // P4: (m4-7 x n2-3)
    STG_B(0, 1, t2);
    asm volatile("s_waitcnt vmcnt(4)" ::: "memory"); // cover P5-P8 reads
    BARRIER();
    MF_(1, b2, 1);
    BARRIER();
    // ---- tile 2*i2+1 (buf1) ----
    // P5
    LDA_(0, 1); LDB_(b, 0, 1);
    STG_A(0, 0, t2);
    BARRIER();
    MF_(0, b, 0);
    BARRIER();
    // P6
    LDB_(b2, 1, 1);
    STG_A(0, 1, t2);
    BARRIER();
    MF_(0, b2, 1);
    BARRIER();
    // P7
    LDA_(1, 1);
    STG_B(1, 0, t3);
    BARRIER();
    MF_(1, b, 0);
    BARRIER();
    // P8
    STG_B(1, 1, t3);
    asm volatile("s_waitcnt vmcnt(4)" ::: "memory"); // cover next P1-P4 reads
    BARRIER();
    MF_(1, b2, 1);
    BARRIER();
  }
  asm volatile("s_waitcnt vmcnt(0)" ::: "memory");   // drain tail stages
#undef STG_A
#undef STG_B
#undef LDA_
#undef LDB_
#undef MF_
#undef BARRIER

  int sel = n0 >> 10;                 // uniform per block (256 | 1024)
  const float* bp = (sel == 0) ? bq : (sel == 1) ? bk : bv;
  float scl = (sel == 0) ? 0.125f * LOG2E : 1.0f;

  #pragma unroll
  for (int n = 0; n < 4; ++n) {
    int nn = (n0 & 1023) + wc * 64 + n * 16 + c;
    float bias = bp[nn];
    int h = nn >> 6, d = nn & 63;
    #pragma unroll
    for (int m = 0; m < 8; ++m) {
      int rowg = m0 + wr * 128 + m * 16 + g * 4;
      int bb = rowg >> 10;
      int s = rowg & 1023;
      #pragma unroll
      for (int r = 0; r < 4; ++r) {
        float val = (acc[m][n][r] + bias) * scl;
        unsigned short ob = f2bf(val);
        if (sel == 0)
          Q[(size_t)((bb * 16 + h) * 1024 + s + r) * 64 + d] = ob;
        else if (sel == 1)
          K[(size_t)((bb * 16 + h) * 1024 + s + r) * 64 + d] = ob;
        else
          Vt[(size_t)((bb * 16 + h) * 64 + d) * 1024 + s + r] = ob;
      }
    }
  }
}

// Build two PV A-fragments from 16 P values (C-layout) — 8 cvt_pk + 4
// permlane32_swap, no LDS.
__device__ __forceinline__ void build_pa(const f32x16& p, bf16x8& pa0, bf16x8& pa1) {
  unsigned W0 = cvtpk(p[0],  p[1]);
  unsigned W1 = cvtpk(p[2],  p[3]);
  unsigned W2 = cvtpk(p[4],  p[5]);
  unsigned W3 = cvtpk(p[6],  p[7]);
  unsigned W4 = cvtpk(p[8],  p[9]);
  unsigned W5 = cvtpk(p[10], p[11]);
  unsigned W6 = cvtpk(p[12], p[13]);
  unsigned W7 = cvtpk(p[14], p[15]);
  pl32swap(W0, W2);
  pl32swap(W1, W3);
  pl32swap(W4, W6);
  pl32swap(W5, W7);
  union { unsigned u[4]; bf16x8 v; } a0, a1;
  a0.u[0] = W0; a0.u[1] = W1; a0.u[2] = W2; a0.u[3] = W3;
  a1.u[0] = W4; a1.u[1] = W5; a1.u[2] = W6; a1.u[3] = W7;
  pa0 = a0.v; pa1 = a1.v;
}

// ---------------- flash attention, 32x32 swapped orientation ----------------
// Triple-buffered K/V staging, 1 barrier/iter, mask in LDS (vmcnt stays clean).
__global__ __launch_bounds__(256) void attn(
    const ushort* __restrict__ Q,    // [B*H][S][64], pre-scaled 0.125*log2e
    const ushort* __restrict__ K,    // [B*H][S][64]
    const ushort* __restrict__ Vt,   // [B*H][64][S]
    const float* __restrict__ mask,  // [B][S]
    float* __restrict__ out)         // [B][S][1024]
{
  __shared__ __attribute__((aligned(16))) char kv_lds[3][16384]; // [K 8K][V 8K] x3
  __shared__ float mask_s[SS];                                   // 4 KB (log2-domain)

  int blk = blockIdx.x;           // 512
  int xcd = blk & 7;
  int j = blk >> 3;               // 0..63
  int bh = xcd * 8 + (j >> 3);    // 8 heads per XCD
  int qt = j & 7;
  int b = bh >> 4, h = bh & 15;
  int tid = threadIdx.x, wave = tid >> 6, lane = tid & 63;
  int r31 = lane & 31, hi = lane >> 5;
  int rsw = r31 & 7;
  int hib = hi << 4;
  int q0 = qt * 128 + wave * 32;

  const ushort* Qb = Q + (size_t)bh * SS * 64;
  const ushort* Kb = K + (size_t)bh * SS * 64;
  const ushort* Vb = Vt + (size_t)bh * 64 * SS;

  for (int i = tid; i < SS; i += 256) mask_s[i] = mask[b * SS + i] * LOG2E;

  bf16x8 qf[4];
  #pragma unroll
  for (int kp = 0; kp < 4; ++kp)
    qf[kp] = *(const bf16x8*)(Qb + (size_t)(q0 + r31) * 64 + kp * 16 + hi * 8);

  int srow = lane >> 3;
  int schunk = lane & 7;
  const ushort* sptr[4];
  int soff[4];
  #pragma unroll
  for (int j2 = 0; j2 < 4; ++j2) {
    soff[j2] = wave * 4096 + j2 * 1024;
    if (wave < 2) {
      int row = wave * 32 + j2 * 8 + srow;
      sptr[j2] = Kb + (size_t)row * 64 + ((schunk ^ srow) << 3);
    } else {
      int d = (wave - 2) * 32 + j2 * 8 + srow;
      sptr[j2] = Vb + (size_t)d * SS + ((schunk ^ srow) << 3);
    }
  }
  const int sstep = (wave < 2) ? 64 * 64 : 64;

#define STAGE(bufidx) do {                              \
    char* lb_ = kv_lds[bufidx];                         \
    async16(lb_ + soff[0], sptr[0]);                    \
    async16(lb_ + soff[1], sptr[1]);                    \
    async16(lb_ + soff[2], sptr[2]);                    \
    async16(lb_ + soff[3], sptr[3]);                    \
    sptr[0] += sstep; sptr[1] += sstep;                 \
    sptr[2] += sstep; sptr[3] += sstep;                 \
  } while (0)

  __syncthreads();                // mask_s visible to all waves
  STAGE(0);                       // prologue: 2 tiles in flight
  STAGE(1);

  f32x16 o0 = (f32x16)0.0f, o1 = (f32x16)0.0f;
  float mrow = 0.f, lrow = 0.f;

  int cur = 0, nxt = 2;
  for (int it = 0; it < 16; ++it) {
    if (it < 15) {
      asm volatile("s_waitcnt vmcnt(4)" ::: "memory");
    } else {
      asm volatile("s_waitcnt vmcnt(0)" ::: "memory");
    }
    __builtin_amdgcn_sched_barrier(0);
    __builtin_amdgcn_s_barrier();
    __builtin_amdgcn_sched_barrier(0);
    if (it < 14) STAGE(nxt);

    const char* kb0 = kv_lds[cur];
    const char* vb0 = kv_lds[cur] + 8192;

    f32x16 s0 = (f32x16)0.0f, s1 = (f32x16)0.0f;
    __builtin_amdgcn_s_setprio(1);
    #pragma unroll
    for (int kp = 0; kp < 4; ++kp) {
      int ch = (((kp << 1) | hi) ^ rsw) << 4;
      bf16x8 ka = *(const bf16x8*)(kb0 + r31 * 128 + ch);
      bf16x8 kc = *(const bf16x8*)(kb0 + (32 + r31) * 128 + ch);
      s0 = __builtin_amdgcn_mfma_f32_32x32x16_bf16(ka, qf[kp], s0, 0, 0, 0);
      s1 = __builtin_amdgcn_mfma_f32_32x32x16_bf16(kc, qf[kp], s1, 0, 0, 0);
    }
    __builtin_amdgcn_s_setprio(0);

    int kv = it * 64;
    #pragma unroll
    for (int sq = 0; sq < 4; ++sq) {
      f32x4 mk0 = *(const f32x4*)(&mask_s[kv + sq * 8 + hi * 4]);
      f32x4 mk1 = *(const f32x4*)(&mask_s[kv + 32 + sq * 8 + hi * 4]);
      #pragma unroll
      for (int r = 0; r < 4; ++r) {
        s0[sq * 4 + r] += mk0[r];
        s1[sq * 4 + r] += mk1[r];
      }
    }

    float mx = s0[0];
    #pragma unroll
    for (int i = 1; i < 16; ++i) mx = fmaxf(mx, s0[i]);
    #pragma unroll
    for (int i = 0; i < 16; ++i) mx = fmaxf(mx, s1[i]);
    mx = fmaxf(mx, __shfl_xor(mx, 32));

    if (!__all(mx <= mrow + 11.5416f)) {
      float mn = fmaxf(mrow, mx);
      float sc = exp2fast(mrow - mn);
      mrow = mn;
      lrow *= sc;
      #pragma unroll
      for (int i = 0; i < 16; ++i) {
        int qh = (i & 3) + 8 * (i >> 2);
        float scq = __uint_as_float((unsigned)__builtin_amdgcn_ds_bpermute(
            (qh << 2) + hib, (int)__float_as_uint(sc)));
        o0[i] *= scq; o1[i] *= scq;
      }
    }

    f32x16 p0, p1;
    float rs = 0.f;
    #pragma unroll
    for (int i = 0; i < 16; ++i) { float e = exp2fast(s0[i] - mrow); p0[i] = e; rs += e; }
    #pragma unroll
    for (int i = 0; i < 16; ++i) { float e = exp2fast(s1[i] - mrow); p1[i] = e; rs += e; }
    rs += __shfl_xor(rs, 32);
    lrow += rs;

    #pragma unroll
    for (int T = 0; T < 2; ++T) {
      bf16x8 pa0, pa1;
      build_pa(T ? p1 : p0, pa0, pa1);
      __builtin_amdgcn_s_setprio(1);
      #pragma unroll
      for (int kh = 0; kh < 2; ++kh) {
        int kap = 2 * T + kh;
        int ch = (((kap << 1) | hi) ^ rsw) << 4;
        bf16x8 va = *(const bf16x8*)(vb0 + r31 * 128 + ch);
        bf16x8 vc = *(const bf16x8*)(vb0 + (32 + r31) * 128 + ch);
        bf16x8 pf = kh ? pa1 : pa0;
        o0 = __builtin_amdgcn_mfma_f32_32x32x16_bf16(pf, va, o0, 0, 0, 0);
        o1 = __builtin_amdgcn_mfma_f32_32x32x16_bf16(pf, vc, o1, 0, 0, 0);
      }
      __builtin_amdgcn_s_setprio(0);
    }

    cur = (cur == 2) ? 0 : cur + 1;
    nxt = (nxt == 2) ? 0 : nxt + 1;
  }
#undef STAGE

  float inv = 1.0f / lrow;
  #pragma unroll
  for (int i = 0; i < 16; ++i) {
    int qh = (i & 3) + 8 * (i >> 2);
    float li = __uint_as_float((unsigned)__builtin_amdgcn_ds_bpermute(
        (qh << 2) + hib, (int)__float_as_uint(inv)));
    int row = q0 + qh + 4 * hi;
    float* op = out + (size_t)(b * SS + row) * 1024 + h * 64 + r31;
    op[0]  = o0[i] * li;
    op[32] = o1[i] * li;
  }
}

extern "C" void kernel_launch(void* const* d_in, const int* in_sizes, int n_in,
                              void* d_out, int out_size, void* d_ws, size_t ws_size,
                              hipStream_t stream) {
  const float* hs   = (const float*)d_in[0];
  const float* mask = (const float*)d_in[1];
  const float* Wq   = (const float*)d_in[2];
  const float* bq   = (const float*)d_in[3];
  const float* Wk   = (const float*)d_in[4];
  const float* bk   = (const float*)d_in[5];
  const float* Wv   = (const float*)d_in[6];
  const float* bv   = (const float*)d_in[7];
  float* out = (float*)d_out;

  char* ws = (char*)d_ws;
  ushort* Xb = (ushort*)(ws);                    // 8 MB  [4096][1024]
  ushort* Wb = (ushort*)(ws + (8u  << 20));      // 6 MB  [3072][1024]
  ushort* Qp = (ushort*)(ws + (14u << 20));      // 8 MB  [64][1024][64]
  ushort* Kp = (ushort*)(ws + (22u << 20));      // 8 MB  [64][1024][64]
  ushort* Vt = (ushort*)(ws + (30u << 20));      // 8 MB  [64][64][1024]

  cvt_all<<<7168, 256, 0, stream>>>((const float4*)hs, (const float4*)Wq,
                                    (const float4*)Wk, (const float4*)Wv,
                                    (ushort4*)Xb, (ushort4*)Wb);
  qkv_gemm<<<192, 512, 0, stream>>>(Xb, Wb, bq, bk, bv, Qp, Kp, Vt);
  attn<<<512, 256, 0, stream>>>(Qp, Kp, Vt, mask, out);
}

// Round 9
// 93.100 us; speedup vs baseline: 1.3427x; 1.0622x over previous
//
#include <hip/hip_runtime.h>
#include <hip/hip_bf16.h>
#include <stdint.h>

#define NH 16
#define HID 1024
#define HD 64
#define NB 4
#define SS 1024
#define MTOT (NB*SS)   // 4096

typedef __attribute__((ext_vector_type(8))) short bf16x8;
typedef __attribute__((ext_vector_type(4))) float f32x4;
typedef __attribute__((ext_vector_type(16))) float f32x16;

#define LOG2E 1.44269504088896f

__device__ __forceinline__ unsigned short f2bf(float f) {
  union { float f; unsigned u; } v; v.f = f;
  unsigned u = v.u;
  return (unsigned short)((u + 0x7FFFu + ((u >> 16) & 1u)) >> 16);
}

__device__ __forceinline__ unsigned cvtpk(float lo, float hi) {
  unsigned r;
  asm("v_cvt_pk_bf16_f32 %0, %1, %2" : "=v"(r) : "v"(lo), "v"(hi));
  return r;
}

__device__ __forceinline__ void pl32swap(unsigned &a, unsigned &b) {
  asm("v_permlane32_swap_b32 %0, %1" : "+v"(a), "+v"(b));
}

__device__ __forceinline__ float exp2fast(float x) {
  float r;
  asm("v_exp_f32 %0, %1" : "=v"(r) : "v"(x));
  return r;
}

__device__ __forceinline__ void async16(void* lds, const void* g) {
  __builtin_amdgcn_global_load_lds(
      (const __attribute__((address_space(1))) unsigned*)g,
      (__attribute__((address_space(3))) unsigned*)lds, 16, 0, 0);
}

// ---------------- fp32 -> bf16 conversion of X and W ----------------
__global__ void cvt_all(const float4* __restrict__ X,
                        const float4* __restrict__ Wq,
                        const float4* __restrict__ Wk,
                        const float4* __restrict__ Wv,
                        ushort4* __restrict__ Xb,
                        ushort4* __restrict__ Wb) {
  int i = blockIdx.x * 256 + threadIdx.x;   // 1835008 total
  const float4* src; ushort4* dst; int idx;
  if (i < (MTOT * HID / 4)) {
    src = X; dst = Xb; idx = i;
  } else {
    int j = i - (MTOT * HID / 4);
    int sel = j >> 18;
    idx = j & 262143;
    src = (sel == 0) ? Wq : (sel == 1) ? Wk : Wv;
    dst = Wb + (size_t)sel * 262144;
  }
  float4 v = src[idx];
  ushort4 o;
  o.x = f2bf(v.x); o.y = f2bf(v.y); o.z = f2bf(v.z); o.w = f2bf(v.w);
  dst[idx] = o;
}

// ---------------- fused QKV projection GEMM ----------------
// BM=128 x BN=64, 128 threads (2 waves x 64x64), BK=32 double-buffered,
// 24 KB LDS -> 6 blocks/CU, grid 1536 = 6/CU exact. Counted vmcnt(6),
// XOR-swizzled LDS. Q pre-scaled by 0.125*log2(e) (exp2-domain softmax).
__global__ __launch_bounds__(128) void qkv_gemm(
    const ushort* __restrict__ Xb,    // [4096][1024] bf16
    const ushort* __restrict__ Wb,    // [3072][1024] bf16 (Wq|Wk|Wv)
    const float* __restrict__ bq,
    const float* __restrict__ bk,
    const float* __restrict__ bv,
    ushort* __restrict__ Q,           // [B*H][S][64]
    ushort* __restrict__ K,           // [B*H][S][64]
    ushort* __restrict__ Vt)          // [B*H][64][S]
{
  __shared__ __attribute__((aligned(16))) ushort Al[2][128 * 32]; // 2x8KB
  __shared__ __attribute__((aligned(16))) ushort Bl[2][64 * 32];  // 2x4KB

  int bid = blockIdx.x;               // 1536 blocks
  int swz = (bid & 7) * 192 + (bid >> 3);  // XCD swizzle (1536 % 8 == 0)
  int bm = swz / 48, bn = swz % 48;   // 32 x 48 tiles
  int m0 = bm * 128, n0 = bn * 64;

  int tid = threadIdx.x;
  int wave = tid >> 6, lane = tid & 63;
  int g = lane >> 4, c = lane & 15;

  // staging: A = 128x32 (8KB, 4 loads/thr), B = 64x32 (4KB, 2 loads/thr).
  // LDS dest linear (dst = tid*16 + i*2048); bank swizzle via XOR on the
  // GLOBAL 16B-chunk: position p of row r holds chunk p ^ ((r>>1)&3).
  int r0 = tid >> 2;                  // 0..31
  int ck = tid & 3;
  int gck = ck ^ ((r0 >> 1) & 3);     // invariant to row+32k
  const ushort* As[4];
  const ushort* Bs[2];
  #pragma unroll
  for (int i = 0; i < 4; ++i)
    As[i] = Xb + (size_t)(m0 + r0 + 32 * i) * 1024 + gck * 8;
  #pragma unroll
  for (int i = 0; i < 2; ++i)
    Bs[i] = Wb + (size_t)(n0 + r0 + 32 * i) * 1024 + gck * 8;
  int sdst = tid * 16;

#define GSTAGE(bi) do {                                   \
    char* la_ = (char*)Al[bi]; char* lb_ = (char*)Bl[bi]; \
    async16(la_ + sdst,        As[0]);                    \
    async16(la_ + 2048 + sdst, As[1]);                    \
    async16(la_ + 4096 + sdst, As[2]);                    \
    async16(la_ + 6144 + sdst, As[3]);                    \
    async16(lb_ + sdst,        Bs[0]);                    \
    async16(lb_ + 2048 + sdst, Bs[1]);                    \
    As[0] += 32; As[1] += 32; As[2] += 32; As[3] += 32;   \
    Bs[0] += 32; Bs[1] += 32;                             \
  } while (0)

  f32x4 acc[4][4] = {};
  int rsw = (c >> 1) & 3;             // read-side swizzle
  int ch = ((g ^ rsw) << 4);          // swizzled 16B chunk byte offset

  GSTAGE(0);                          // prologue: step 0 in flight

  int cur = 0;
  for (int ks = 0; ks < 32; ++ks) {
    if (ks < 31) {
      GSTAGE(cur ^ 1);                // next step's 6 loads stay in flight
      asm volatile("s_waitcnt vmcnt(6)" ::: "memory");
    } else {
      asm volatile("s_waitcnt vmcnt(0)" ::: "memory");
    }
    __builtin_amdgcn_sched_barrier(0);
    __builtin_amdgcn_s_barrier();     // both waves: cur tile complete
    __builtin_amdgcn_sched_barrier(0);

    const char* la = (const char*)Al[cur];
    const char* lb = (const char*)Bl[cur];
    bf16x8 a[4], b[4];
    #pragma unroll
    for (int m = 0; m < 4; ++m)
      a[m] = *(const bf16x8*)(la + (wave * 64 + m * 16 + c) * 64 + ch);
    #pragma unroll
    for (int n = 0; n < 4; ++n)
      b[n] = *(const bf16x8*)(lb + (n * 16 + c) * 64 + ch);
    __builtin_amdgcn_s_setprio(1);
    #pragma unroll
    for (int m = 0; m < 4; ++m)
      #pragma unroll
      for (int n = 0; n < 4; ++n)
        acc[m][n] = __builtin_amdgcn_mfma_f32_16x16x32_bf16(a[m], b[n], acc[m][n], 0, 0, 0);
    __builtin_amdgcn_s_setprio(0);

    __builtin_amdgcn_sched_barrier(0);
    __builtin_amdgcn_s_barrier();     // reads done before next STAGE overwrites
    cur ^= 1;
  }
#undef GSTAGE

  int sel = n0 >> 10;                 // uniform per block (64 | 1024)
  const float* bp = (sel == 0) ? bq : (sel == 1) ? bk : bv;
  float scl = (sel == 0) ? 0.125f * LOG2E : 1.0f;
  int h = (n0 & 1023) >> 6;           // block-uniform head

  #pragma unroll
  for (int n = 0; n < 4; ++n) {
    int d = n * 16 + c;               // dim within head
    float bias = bp[(n0 & 1023) + d];
    #pragma unroll
    for (int m = 0; m < 4; ++m) {
      int rowg = m0 + wave * 64 + m * 16 + g * 4;
      int bb = rowg >> 10;
      int s = rowg & 1023;
      #pragma unroll
      for (int r = 0; r < 4; ++r) {
        float val = (acc[m][n][r] + bias) * scl;
        unsigned short ob = f2bf(val);
        if (sel == 0)
          Q[(size_t)((bb * 16 + h) * 1024 + s + r) * 64 + d] = ob;
        else if (sel == 1)
          K[(size_t)((bb * 16 + h) * 1024 + s + r) * 64 + d] = ob;
        else
          Vt[(size_t)((bb * 16 + h) * 64 + d) * 1024 + s + r] = ob;
      }
    }
  }
}

// Build two PV A-fragments from 16 P values (C-layout) — 8 cvt_pk + 4
// permlane32_swap, no LDS.
__device__ __forceinline__ void build_pa(const f32x16& p, bf16x8& pa0, bf16x8& pa1) {
  unsigned W0 = cvtpk(p[0],  p[1]);
  unsigned W1 = cvtpk(p[2],  p[3]);
  unsigned W2 = cvtpk(p[4],  p[5]);
  unsigned W3 = cvtpk(p[6],  p[7]);
  unsigned W4 = cvtpk(p[8],  p[9]);
  unsigned W5 = cvtpk(p[10], p[11]);
  unsigned W6 = cvtpk(p[12], p[13]);
  unsigned W7 = cvtpk(p[14], p[15]);
  pl32swap(W0, W2);
  pl32swap(W1, W3);
  pl32swap(W4, W6);
  pl32swap(W5, W7);
  union { unsigned u[4]; bf16x8 v; } a0, a1;
  a0.u[0] = W0; a0.u[1] = W1; a0.u[2] = W2; a0.u[3] = W3;
  a1.u[0] = W4; a1.u[1] = W5; a1.u[2] = W6; a1.u[3] = W7;
  pa0 = a0.v; pa1 = a1.v;
}

// ---------------- flash attention, 32x32 swapped orientation ----------------
// Triple-buffered K/V staging, 1 barrier/iter, mask in LDS (vmcnt stays clean).
__global__ __launch_bounds__(256) void attn(
    const ushort* __restrict__ Q,    // [B*H][S][64], pre-scaled 0.125*log2e
    const ushort* __restrict__ K,    // [B*H][S][64]
    const ushort* __restrict__ Vt,   // [B*H][64][S]
    const float* __restrict__ mask,  // [B][S]
    float* __restrict__ out)         // [B][S][1024]
{
  __shared__ __attribute__((aligned(16))) char kv_lds[3][16384]; // [K 8K][V 8K] x3
  __shared__ float mask_s[SS];                                   // 4 KB (log2-domain)

  int blk = blockIdx.x;           // 512
  int xcd = blk & 7;
  int j = blk >> 3;               // 0..63
  int bh = xcd * 8 + (j >> 3);    // 8 heads per XCD
  int qt = j & 7;
  int b = bh >> 4, h = bh & 15;
  int tid = threadIdx.x, wave = tid >> 6, lane = tid & 63;
  int r31 = lane & 31, hi = lane >> 5;
  int rsw = r31 & 7;
  int hib = hi << 4;
  int q0 = qt * 128 + wave * 32;

  const ushort* Qb = Q + (size_t)bh * SS * 64;
  const ushort* Kb = K + (size_t)bh * SS * 64;
  const ushort* Vb = Vt + (size_t)bh * 64 * SS;

  for (int i = tid; i < SS; i += 256) mask_s[i] = mask[b * SS + i] * LOG2E;

  bf16x8 qf[4];
  #pragma unroll
  for (int kp = 0; kp < 4; ++kp)
    qf[kp] = *(const bf16x8*)(Qb + (size_t)(q0 + r31) * 64 + kp * 16 + hi * 8);

  int srow = lane >> 3;
  int schunk = lane & 7;
  const ushort* sptr[4];
  int soff[4];
  #pragma unroll
  for (int j2 = 0; j2 < 4; ++j2) {
    soff[j2] = wave * 4096 + j2 * 1024;
    if (wave < 2) {
      int row = wave * 32 + j2 * 8 + srow;
      sptr[j2] = Kb + (size_t)row * 64 + ((schunk ^ srow) << 3);
    } else {
      int d = (wave - 2) * 32 + j2 * 8 + srow;
      sptr[j2] = Vb + (size_t)d * SS + ((schunk ^ srow) << 3);
    }
  }
  const int sstep = (wave < 2) ? 64 * 64 : 64;

#define STAGE(bufidx) do {                              \
    char* lb_ = kv_lds[bufidx];                         \
    async16(lb_ + soff[0], sptr[0]);                    \
    async16(lb_ + soff[1], sptr[1]);                    \
    async16(lb_ + soff[2], sptr[2]);                    \
    async16(lb_ + soff[3], sptr[3]);                    \
    sptr[0] += sstep; sptr[1] += sstep;                 \
    sptr[2] += sstep; sptr[3] += sstep;                 \
  } while (0)

  __syncthreads();                // mask_s visible to all waves
  STAGE(0);                       // prologue: 2 tiles in flight
  STAGE(1);

  f32x16 o0 = (f32x16)0.0f, o1 = (f32x16)0.0f;
  float mrow = 0.f, lrow = 0.f;

  int cur = 0, nxt = 2;
  for (int it = 0; it < 16; ++it) {
    if (it < 15) {
      asm volatile("s_waitcnt vmcnt(4)" ::: "memory");
    } else {
      asm volatile("s_waitcnt vmcnt(0)" ::: "memory");
    }
    __builtin_amdgcn_sched_barrier(0);
    __builtin_amdgcn_s_barrier();
    __builtin_amdgcn_sched_barrier(0);
    if (it < 14) STAGE(nxt);

    const char* kb0 = kv_lds[cur];
    const char* vb0 = kv_lds[cur] + 8192;

    f32x16 s0 = (f32x16)0.0f, s1 = (f32x16)0.0f;
    __builtin_amdgcn_s_setprio(1);
    #pragma unroll
    for (int kp = 0; kp < 4; ++kp) {
      int ch = (((kp << 1) | hi) ^ rsw) << 4;
      bf16x8 ka = *(const bf16x8*)(kb0 + r31 * 128 + ch);
      bf16x8 kc = *(const bf16x8*)(kb0 + (32 + r31) * 128 + ch);
      s0 = __builtin_amdgcn_mfma_f32_32x32x16_bf16(ka, qf[kp], s0, 0, 0, 0);
      s1 = __builtin_amdgcn_mfma_f32_32x32x16_bf16(kc, qf[kp], s1, 0, 0, 0);
    }
    __builtin_amdgcn_s_setprio(0);

    int kv = it * 64;
    #pragma unroll
    for (int sq = 0; sq < 4; ++sq) {
      f32x4 mk0 = *(const f32x4*)(&mask_s[kv + sq * 8 + hi * 4]);
      f32x4 mk1 = *(const f32x4*)(&mask_s[kv + 32 + sq * 8 + hi * 4]);
      #pragma unroll
      for (int r = 0; r < 4; ++r) {
        s0[sq * 4 + r] += mk0[r];
        s1[sq * 4 + r] += mk1[r];
      }
    }

    float mx = s0[0];
    #pragma unroll
    for (int i = 1; i < 16; ++i) mx = fmaxf(mx, s0[i]);
    #pragma unroll
    for (int i = 0; i < 16; ++i) mx = fmaxf(mx, s1[i]);
    mx = fmaxf(mx, __shfl_xor(mx, 32));

    if (!__all(mx <= mrow + 11.5416f)) {
      float mn = fmaxf(mrow, mx);
      float sc = exp2fast(mrow - mn);
      mrow = mn;
      lrow *= sc;
      #pragma unroll
      for (int i = 0; i < 16; ++i) {
        int qh = (i & 3) + 8 * (i >> 2);
        float scq = __uint_as_float((unsigned)__builtin_amdgcn_ds_bpermute(
            (qh << 2) + hib, (int)__float_as_uint(sc)));
        o0[i] *= scq; o1[i] *= scq;
      }
    }

    f32x16 p0, p1;
    float rs = 0.f;
    #pragma unroll
    for (int i = 0; i < 16; ++i) { float e = exp2fast(s0[i] - mrow); p0[i] = e; rs += e; }
    #pragma unroll
    for (int i = 0; i < 16; ++i) { float e = exp2fast(s1[i] - mrow); p1[i] = e; rs += e; }
    rs += __shfl_xor(rs, 32);
    lrow += rs;

    #pragma unroll
    for (int T = 0; T < 2; ++T) {
      bf16x8 pa0, pa1;
      build_pa(T ? p1 : p0, pa0, pa1);
      __builtin_amdgcn_s_setprio(1);
      #pragma unroll
      for (int kh = 0; kh < 2; ++kh) {
        int kap = 2 * T + kh;
        int ch = (((kap << 1) | hi) ^ rsw) << 4;
        bf16x8 va = *(const bf16x8*)(vb0 + r31 * 128 + ch);
        bf16x8 vc = *(const bf16x8*)(vb0 + (32 + r31) * 128 + ch);
        bf16x8 pf = kh ? pa1 : pa0;
        o0 = __builtin_amdgcn_mfma_f32_32x32x16_bf16(pf, va, o0, 0, 0, 0);
        o1 = __builtin_amdgcn_mfma_f32_32x32x16_bf16(pf, vc, o1, 0, 0, 0);
      }
      __builtin_amdgcn_s_setprio(0);
    }

    cur = (cur == 2) ? 0 : cur + 1;
    nxt = (nxt == 2) ? 0 : nxt + 1;
  }
#undef STAGE

  float inv = 1.0f / lrow;
  #pragma unroll
  for (int i = 0; i < 16; ++i) {
    int qh = (i & 3) + 8 * (i >> 2);
    float li = __uint_as_float((unsigned)__builtin_amdgcn_ds_bpermute(
        (qh << 2) + hib, (int)__float_as_uint(inv)));
    int row = q0 + qh + 4 * hi;
    float* op = out + (size_t)(b * SS + row) * 1024 + h * 64 + r31;
    op[0]  = o0[i] * li;
    op[32] = o1[i] * li;
  }
}

extern "C" void kernel_launch(void* const* d_in, const int* in_sizes, int n_in,
                              void* d_out, int out_size, void* d_ws, size_t ws_size,
                              hipStream_t stream) {
  const float* hs   = (const float*)d_in[0];
  const float* mask = (const float*)d_in[1];
  const float* Wq   = (const float*)d_in[2];
  const float* bq   = (const float*)d_in[3];
  const float* Wk   = (const float*)d_in[4];
  const float* bk   = (const float*)d_in[5];
  const float* Wv   = (const float*)d_in[6];
  const float* bv   = (const float*)d_in[7];
  float* out = (float*)d_out;

  char* ws = (char*)d_ws;
  ushort* Xb = (ushort*)(ws);                    // 8 MB  [4096][1024]
  ushort* Wb = (ushort*)(ws + (8u  << 20));      // 6 MB  [3072][1024]
  ushort* Qp = (ushort*)(ws + (14u << 20));      // 8 MB  [64][1024][64]
  ushort* Kp = (ushort*)(ws + (22u << 20));      // 8 MB  [64][1024][64]
  ushort* Vt = (ushort*)(ws + (30u << 20));      // 8 MB  [64][64][1024]

  cvt_all<<<7168, 256, 0, stream>>>((const float4*)hs, (const float4*)Wq,
                                    (const float4*)Wk, (const float4*)Wv,
                                    (ushort4*)Xb, (ushort4*)Wb);
  qkv_gemm<<<1536, 128, 0, stream>>>(Xb, Wb, bq, bk, bv, Qp, Kp, Vt);
  attn<<<512, 256, 0, stream>>>(Qp, Kp, Vt, mask, out);
}